// Round 3
// baseline (349.152 us; speedup 1.0000x reference)
//
#include <hip/hip_runtime.h>

// YOLO head: input [B, 255, 80, 80] f32, anchors [3,2] f32
// output [B, 3*80*80, 85] f32.
// out[b, a*6400 + h*80 + w, c] = f(in[b, a*85 + c, h, w]) where
//   c==0: (sigmoid(x)+w)*8   c==1: (sigmoid(x)+h)*8
//   c==2: exp(clip(x,±16))*anchor_w[a]   c==3: exp(clip(x,±16))*anchor_h[a]
//   c>=4: sigmoid(x)
// Memory-bound transpose: stage per-(b,a,h) 80x85 tile in LDS in OUTPUT-LINEAR
// layout so the store phase is pure ds_read_b128 + global_store_dwordx4.

#define NA 3
#define ATTRS 85
#define GH 80
#define GW 80
#define HW 6400            // GH*GW
#define CIN (NA * ATTRS)   // 255
#define STRIDE_PX 8.0f     // 640/80

constexpr int TILE_ELEMS = ATTRS * GW;       // 6800 floats per block tile
constexpr int TILE_F4    = TILE_ELEMS / 4;   // 1700

__device__ __forceinline__ float sigmoidf_acc(float x) {
    return 1.0f / (1.0f + expf(-x));
}

__global__ __launch_bounds__(256) void yolo_head_kernel(
    const float* __restrict__ in,
    const float* __restrict__ anchors,
    float* __restrict__ out)
{
    __shared__ float tile[TILE_ELEMS];   // [w][c] linear, 27200 B

    const int bid = blockIdx.x;
    const int h   = bid % GH;
    const int t2  = bid / GH;
    const int a   = t2 % NA;
    const int b   = t2 / NA;

    const float aw = anchors[2 * a + 0];
    const float ah = anchors[2 * a + 1];

    // input base for (b, a, channel 0, row h)
    const float* src = in + ((size_t)(b * CIN + a * ATTRS)) * HW + h * GW;

    // ---- load + transform: 1700 float4 coalesced reads ----
    for (int li = threadIdx.x; li < TILE_F4; li += 256) {
        const int c = li / (GW / 4);        // channel 0..84
        const int v = li % (GW / 4);        // float4 index within row
        const float4 x4 =
            *reinterpret_cast<const float4*>(src + (size_t)c * HW + v * 4);
        const float xs[4] = {x4.x, x4.y, x4.z, x4.w};
        #pragma unroll
        for (int j = 0; j < 4; ++j) {
            const int w = v * 4 + j;
            const float x = xs[j];
            float r;
            if (c == 0) {
                r = (sigmoidf_acc(x) + (float)w) * STRIDE_PX;
            } else if (c == 1) {
                r = (sigmoidf_acc(x) + (float)h) * STRIDE_PX;
            } else if (c == 2) {
                r = expf(fminf(fmaxf(x, -16.0f), 16.0f)) * aw;
            } else if (c == 3) {
                r = expf(fminf(fmaxf(x, -16.0f), 16.0f)) * ah;
            } else {
                r = sigmoidf_acc(x);
            }
            tile[w * ATTRS + c] = r;        // output-linear scatter
        }
    }

    __syncthreads();

    // ---- store: 1700 float4 LDS b128 reads + fully-coalesced global writes ----
    // block's output region: out[b, a*6400 + h*80 + (0..79), 0..84]
    float4* dst = reinterpret_cast<float4*>(
        out + (size_t)((b * NA + a) * HW + h * GW) * ATTRS);
    const float4* tsrc = reinterpret_cast<const float4*>(tile);
    for (int oi = threadIdx.x; oi < TILE_F4; oi += 256) {
        dst[oi] = tsrc[oi];
    }
}

extern "C" void kernel_launch(void* const* d_in, const int* in_sizes, int n_in,
                              void* d_out, int out_size, void* d_ws, size_t ws_size,
                              hipStream_t stream) {
    const float* in      = (const float*)d_in[0];
    const float* anchors = (const float*)d_in[1];
    float* out           = (float*)d_out;

    const int B = in_sizes[0] / (CIN * HW);   // 32
    const int grid = B * NA * GH;             // 7680 blocks

    yolo_head_kernel<<<grid, 256, 0, stream>>>(in, anchors, out);
}